// Round 1
// baseline (141.744 us; speedup 1.0000x reference)
//
#include <hip/hip_runtime.h>
#include <hip/hip_bf16.h>
#include <stdint.h>

#define TT 2048
#define DD 1024
#define NH 16
#define DK 64

typedef __attribute__((ext_vector_type(8))) short bf16x8;
typedef __attribute__((ext_vector_type(4))) float f32x4;
typedef __attribute__((ext_vector_type(8))) unsigned short u16x8;
typedef __attribute__((ext_vector_type(4))) unsigned short u16x4;

__device__ __forceinline__ unsigned short f2bf(float f) {
  union { float f; unsigned u; } x; x.f = f;
  unsigned r = (x.u + 0x7FFFu + ((x.u >> 16) & 1u)) >> 16;
  return (unsigned short)r;
}

__device__ __forceinline__ void gload16(const void* g, void* l) {
  __builtin_amdgcn_global_load_lds(
      (const __attribute__((address_space(1))) unsigned int*)g,
      (__attribute__((address_space(3))) unsigned int*)l, 16, 0, 0);
}

// ---------------- convert f32 -> bf16 ----------------
__global__ __launch_bounds__(256) void cvt_all(
    const float* __restrict__ q, const float* __restrict__ k, const float* __restrict__ v,
    const float* __restrict__ wq, const float* __restrict__ wk, const float* __restrict__ wv,
    const float* __restrict__ wo,
    unsigned short* __restrict__ oq, unsigned short* __restrict__ ok, unsigned short* __restrict__ ov,
    unsigned short* __restrict__ owq, unsigned short* __restrict__ owk, unsigned short* __restrict__ owv,
    unsigned short* __restrict__ owo) {
  int b = blockIdx.x;
  const float* src; unsigned short* dst; int sb;
  if (b < 1024)      { src = q;  dst = oq;  sb = b; }
  else if (b < 2048) { src = k;  dst = ok;  sb = b - 1024; }
  else if (b < 3072) { src = v;  dst = ov;  sb = b - 2048; }
  else if (b < 3584) { src = wq; dst = owq; sb = b - 3072; }
  else if (b < 4096) { src = wk; dst = owk; sb = b - 3584; }
  else if (b < 4608) { src = wv; dst = owv; sb = b - 4096; }
  else               { src = wo; dst = owo; sb = b - 4608; }
  size_t i0 = (size_t)sb * 2048 + (size_t)threadIdx.x * 8;
  f32x4 a = *(const f32x4*)(src + i0);
  f32x4 c = *(const f32x4*)(src + i0 + 4);
  u16x8 r;
#pragma unroll
  for (int j = 0; j < 4; ++j) { r[j] = f2bf(a[j]); r[j + 4] = f2bf(c[j]); }
  *(u16x8*)(dst + i0) = r;
}

// ---------------- RoPE cos/sin table ----------------
__global__ __launch_bounds__(256) void rope_tab(const int* __restrict__ pos,
                                                float* __restrict__ cosT,
                                                float* __restrict__ sinT) {
  int idx = blockIdx.x * 256 + threadIdx.x;  // 2048*32
  int t = idx >> 5, i = idx & 31;
  float inv = exp2f((float)i * -0.41524101186092028f);  // 10000^(-i/32)
  float ang = (float)pos[t] * inv;
  cosT[idx] = cosf(ang);
  sinT[idx] = sinf(ang);
}

// ---------------- fused QKV projection + RoPE ----------------
// C[t,o] = sum_i X[t,i] * W[o,i]; 128x128 tile, BK=64, 4 waves (2x2 of 64x64)
__global__ __launch_bounds__(256) void gemm_qkv(
    const unsigned short* __restrict__ xq, const unsigned short* __restrict__ xk,
    const unsigned short* __restrict__ xv,
    const unsigned short* __restrict__ wqb, const unsigned short* __restrict__ wkb,
    const unsigned short* __restrict__ wvb,
    unsigned short* __restrict__ Qh, unsigned short* __restrict__ Kh,
    unsigned short* __restrict__ Vt,
    const float* __restrict__ cosT, const float* __restrict__ sinT) {
  __shared__ unsigned short Ash[128 * 64];
  __shared__ unsigned short Bsh[128 * 64];
  const int z = blockIdx.z;
  const unsigned short* A = (z == 0) ? xq : (z == 1) ? xk : xv;
  const unsigned short* W = (z == 0) ? wqb : (z == 1) ? wkb : wvb;
  const int brow = blockIdx.x * 128;
  const int bcol = blockIdx.y * 128;
  const int tid = threadIdx.x;
  const int lane = tid & 63;
  const int w = tid >> 6;
  const int wr = w >> 1, wc = w & 1;
  const char* Ab = (const char*)A + (size_t)brow * (DD * 2);
  const char* Wb = (const char*)W + (size_t)bcol * (DD * 2);
  char* AshB = (char*)Ash;
  char* BshB = (char*)Bsh;
  f32x4 acc[4][4];
#pragma unroll
  for (int mi = 0; mi < 4; ++mi)
#pragma unroll
    for (int ni = 0; ni < 4; ++ni)
#pragma unroll
      for (int r = 0; r < 4; ++r) acc[mi][ni][r] = 0.0f;

  for (int k0 = 0; k0 < DD; k0 += 64) {
    __syncthreads();
#pragma unroll
    for (int it = 0; it < 4; ++it) {
      int c = it * 256 + tid;
      int row = c >> 3;
      int xb = (c & 7) << 4;
      int sxb = xb ^ ((row & 7) << 4);     // inverse-swizzled global source (rule #21)
      int ldso = (it * 256 + (tid & 192)) << 4;  // wave-uniform LDS base
      gload16(Ab + (size_t)row * (DD * 2) + k0 * 2 + sxb, AshB + ldso);
      gload16(Wb + (size_t)row * (DD * 2) + k0 * 2 + sxb, BshB + ldso);
    }
    __syncthreads();
#pragma unroll
    for (int ks = 0; ks < 2; ++ks) {
      bf16x8 af[4], bfr[4];
      int colb = ks * 64 + ((lane >> 4) << 4);
#pragma unroll
      for (int mi = 0; mi < 4; ++mi) {
        int row = wr * 64 + mi * 16 + (lane & 15);
        af[mi] = *(const bf16x8*)(AshB + row * 128 + (colb ^ ((row & 7) << 4)));
      }
#pragma unroll
      for (int ni = 0; ni < 4; ++ni) {
        int row = wc * 64 + ni * 16 + (lane & 15);
        bfr[ni] = *(const bf16x8*)(BshB + row * 128 + (colb ^ ((row & 7) << 4)));
      }
#pragma unroll
      for (int mi = 0; mi < 4; ++mi)
#pragma unroll
        for (int ni = 0; ni < 4; ++ni)
          acc[mi][ni] = __builtin_amdgcn_mfma_f32_16x16x32_bf16(af[mi], bfr[ni], acc[mi][ni], 0, 0, 0);
    }
  }

  const int hcol = bcol + wc * 64;  // 64-aligned -> single head per wave
  const int h = hcol >> 6;
  if (z < 2) {
    unsigned short* OUT = (z == 0) ? Qh : Kh;
    const float sc = (z == 0) ? 0.125f : 1.0f;  // 1/sqrt(64) folded into Q
#pragma unroll
    for (int mi = 0; mi < 4; ++mi) {
#pragma unroll
      for (int r = 0; r < 4; ++r) {
        int t = brow + wr * 64 + mi * 16 + ((lane >> 4) << 2) + r;
#pragma unroll
        for (int ni = 0; ni < 2; ++ni) {
          int dl = ni * 16 + (lane & 15);
          float cv = cosT[t * 32 + dl];
          float sv = sinT[t * 32 + dl];
          float x1 = acc[mi][ni][r];
          float x2 = acc[mi][ni + 2][r];
          size_t base = ((size_t)h * TT + t) * DK + dl;
          OUT[base] = f2bf((x1 * cv - x2 * sv) * sc);
          OUT[base + 32] = f2bf((x2 * cv + x1 * sv) * sc);
        }
      }
    }
  } else {
    // V stored transposed per head: Vt[h][d][t]
#pragma unroll
    for (int mi = 0; mi < 4; ++mi) {
#pragma unroll
      for (int ni = 0; ni < 4; ++ni) {
        int dh = ni * 16 + (lane & 15);
        int t0 = brow + wr * 64 + mi * 16 + ((lane >> 4) << 2);
        u16x4 pk;
#pragma unroll
        for (int r = 0; r < 4; ++r) pk[r] = f2bf(acc[mi][ni][r]);
        *(u16x4*)((char*)Vt + (((size_t)h * DK + dh) * TT + t0) * 2) = pk;
      }
    }
  }
}

// ---------------- causal flash attention ----------------
// grid (qblock 0..15, head 0..15); 4 waves x 32 q-rows; KV tiles of 64
__global__ __launch_bounds__(256) void attn(
    const unsigned short* __restrict__ Qh, const unsigned short* __restrict__ Kh,
    const unsigned short* __restrict__ Vt, unsigned short* __restrict__ AO) {
  __shared__ unsigned short Ksh[64 * 64];
  __shared__ unsigned short Vsh[64 * 64];
  __shared__ unsigned short Psh[4][32 * 64];
  const int qb = blockIdx.x;
  const int h = blockIdx.y;
  const int q0 = qb * 128;
  const int tid = threadIdx.x;
  const int lane = tid & 63;
  const int w = tid >> 6;
  const int q0w = q0 + w * 32;
  char* KshB = (char*)Ksh;
  char* VshB = (char*)Vsh;
  char* PshB = (char*)&Psh[w][0];
  const char* Kb = (const char*)Kh + (size_t)h * TT * DK * 2;
  const char* Vb = (const char*)Vt + (size_t)h * DK * TT * 2;

  bf16x8 qf[2][2];
#pragma unroll
  for (int mi = 0; mi < 2; ++mi)
#pragma unroll
    for (int ks = 0; ks < 2; ++ks) {
      const unsigned short* p =
          Qh + ((size_t)h * TT + q0w + mi * 16 + (lane & 15)) * DK + ks * 32 + ((lane >> 4) << 3);
      qf[mi][ks] = *(const bf16x8*)p;
    }

  f32x4 accO[2][4];
  float mrow[2][4], lrow[2][4];
#pragma unroll
  for (int mi = 0; mi < 2; ++mi) {
#pragma unroll
    for (int ni = 0; ni < 4; ++ni)
#pragma unroll
      for (int r = 0; r < 4; ++r) accO[mi][ni][r] = 0.0f;
#pragma unroll
    for (int r = 0; r < 4; ++r) { mrow[mi][r] = -1e30f; lrow[mi][r] = 0.0f; }
  }

  const int NT = qb * 2 + 2;
  for (int kt = 0; kt < NT; ++kt) {
    const int k0 = kt * 64;
    __syncthreads();
#pragma unroll
    for (int it = 0; it < 2; ++it) {
      int c = it * 256 + tid;
      int row = c >> 3;
      int xb = (c & 7) << 4;
      int sxb = xb ^ ((row & 7) << 4);
      int ldso = (it * 256 + (tid & 192)) << 4;
      gload16(Kb + (size_t)(k0 + row) * (DK * 2) + sxb, KshB + ldso);
      gload16(Vb + (size_t)row * (TT * 2) + k0 * 2 + sxb, VshB + ldso);
    }
    __syncthreads();
    if (k0 <= q0w + 31) {  // wave-uniform causal tile guard
      f32x4 s[2][4];
#pragma unroll
      for (int mi = 0; mi < 2; ++mi)
#pragma unroll
        for (int ni = 0; ni < 4; ++ni)
#pragma unroll
          for (int r = 0; r < 4; ++r) s[mi][ni][r] = 0.0f;
#pragma unroll
      for (int ks = 0; ks < 2; ++ks) {
        int colb = ks * 64 + ((lane >> 4) << 4);
        bf16x8 kf[4];
#pragma unroll
        for (int ni = 0; ni < 4; ++ni) {
          int row = ni * 16 + (lane & 15);
          kf[ni] = *(const bf16x8*)(KshB + row * 128 + (colb ^ ((row & 7) << 4)));
        }
#pragma unroll
        for (int mi = 0; mi < 2; ++mi)
#pragma unroll
          for (int ni = 0; ni < 4; ++ni)
            s[mi][ni] = __builtin_amdgcn_mfma_f32_16x16x32_bf16(qf[mi][ks], kf[ni], s[mi][ni], 0, 0, 0);
      }
      if (k0 + 63 > q0w) {  // partial tile: causal mask
#pragma unroll
        for (int mi = 0; mi < 2; ++mi)
#pragma unroll
          for (int ni = 0; ni < 4; ++ni)
#pragma unroll
            for (int r = 0; r < 4; ++r) {
              int qq = q0w + mi * 16 + ((lane >> 4) << 2) + r;
              int kk = k0 + ni * 16 + (lane & 15);
              if (kk > qq) s[mi][ni][r] = -1e30f;
            }
      }
#pragma unroll
      for (int mi = 0; mi < 2; ++mi) {
        f32x4 rmx = s[mi][0];
#pragma unroll
        for (int ni = 1; ni < 4; ++ni)
#pragma unroll
          for (int r = 0; r < 4; ++r) rmx[r] = fmaxf(rmx[r], s[mi][ni][r]);
#pragma unroll
        for (int d = 1; d < 16; d <<= 1)
#pragma unroll
          for (int r = 0; r < 4; ++r) rmx[r] = fmaxf(rmx[r], __shfl_xor(rmx[r], d, 64));
        float alpha[4];
#pragma unroll
        for (int r = 0; r < 4; ++r) {
          float mo = mrow[mi][r];
          float mn = fmaxf(mo, rmx[r]);
          alpha[r] = __expf(mo - mn);
          mrow[mi][r] = mn;
          lrow[mi][r] *= alpha[r];
        }
#pragma unroll
        for (int ni = 0; ni < 4; ++ni)
#pragma unroll
          for (int r = 0; r < 4; ++r) accO[mi][ni][r] *= alpha[r];
        f32x4 rsum;
#pragma unroll
        for (int r = 0; r < 4; ++r) rsum[r] = 0.0f;
#pragma unroll
        for (int ni = 0; ni < 4; ++ni)
#pragma unroll
          for (int r = 0; r < 4; ++r) {
            float p = __expf(s[mi][ni][r] - mrow[mi][r]);
            s[mi][ni][r] = p;
            rsum[r] += p;
          }
#pragma unroll
        for (int d = 1; d < 16; d <<= 1)
#pragma unroll
          for (int r = 0; r < 4; ++r) rsum[r] += __shfl_xor(rsum[r], d, 64);
#pragma unroll
        for (int r = 0; r < 4; ++r) lrow[mi][r] += rsum[r];
        // write P (bf16) to per-wave LDS, swizzled
#pragma unroll
        for (int ni = 0; ni < 4; ++ni)
#pragma unroll
          for (int r = 0; r < 4; ++r) {
            int row = mi * 16 + ((lane >> 4) << 2) + r;
            int cb = (ni * 16 + (lane & 15)) * 2;
            *(short*)(PshB + row * 128 + (cb ^ ((row & 7) << 4))) = (short)f2bf(s[mi][ni][r]);
          }
      }
      asm volatile("" ::: "memory");  // order P writes before P reads (wave-local, HW in-order LDS)
      // PV: O[q][d] += P[q][k] * V[k][d]  (B-frag reads Vt[d][k], contiguous k)
#pragma unroll
      for (int ks = 0; ks < 2; ++ks) {
        int colb = ks * 64 + ((lane >> 4) << 4);
        bf16x8 pf[2], vf[4];
#pragma unroll
        for (int mi = 0; mi < 2; ++mi) {
          int row = mi * 16 + (lane & 15);
          pf[mi] = *(const bf16x8*)(PshB + row * 128 + (colb ^ ((row & 7) << 4)));
        }
#pragma unroll
        for (int ni = 0; ni < 4; ++ni) {
          int row = ni * 16 + (lane & 15);
          vf[ni] = *(const bf16x8*)(VshB + row * 128 + (colb ^ ((row & 7) << 4)));
        }
#pragma unroll
        for (int mi = 0; mi < 2; ++mi)
#pragma unroll
          for (int ni = 0; ni < 4; ++ni)
            accO[mi][ni] = __builtin_amdgcn_mfma_f32_16x16x32_bf16(pf[mi], vf[ni], accO[mi][ni], 0, 0, 0);
      }
    }
  }
  // epilogue: normalize, store bf16 [t][h*64+d]
#pragma unroll
  for (int mi = 0; mi < 2; ++mi)
#pragma unroll
    for (int ni = 0; ni < 4; ++ni)
#pragma unroll
      for (int r = 0; r < 4; ++r) {
        int t = q0w + mi * 16 + ((lane >> 4) << 2) + r;
        int dh = ni * 16 + (lane & 15);
        float v = accO[mi][ni][r] / lrow[mi][r];
        AO[(size_t)t * DD + h * DK + dh] = f2bf(v);
      }
}

// ---------------- output projection + bias (f32 out) ----------------
__global__ __launch_bounds__(256) void gemm_o(
    const unsigned short* __restrict__ A, const unsigned short* __restrict__ W,
    const float* __restrict__ bias, float* __restrict__ out) {
  __shared__ unsigned short Ash[128 * 64];
  __shared__ unsigned short Bsh[128 * 64];
  const int brow = blockIdx.x * 128;
  const int bcol = blockIdx.y * 128;
  const int tid = threadIdx.x;
  const int lane = tid & 63;
  const int w = tid >> 6;
  const int wr = w >> 1, wc = w & 1;
  const char* Ab = (const char*)A + (size_t)brow * (DD * 2);
  const char* Wb = (const char*)W + (size_t)bcol * (DD * 2);
  char* AshB = (char*)Ash;
  char* BshB = (char*)Bsh;
  f32x4 acc[4][4];
#pragma unroll
  for (int mi = 0; mi < 4; ++mi)
#pragma unroll
    for (int ni = 0; ni < 4; ++ni)
#pragma unroll
      for (int r = 0; r < 4; ++r) acc[mi][ni][r] = 0.0f;

  for (int k0 = 0; k0 < DD; k0 += 64) {
    __syncthreads();
#pragma unroll
    for (int it = 0; it < 4; ++it) {
      int c = it * 256 + tid;
      int row = c >> 3;
      int xb = (c & 7) << 4;
      int sxb = xb ^ ((row & 7) << 4);
      int ldso = (it * 256 + (tid & 192)) << 4;
      gload16(Ab + (size_t)row * (DD * 2) + k0 * 2 + sxb, AshB + ldso);
      gload16(Wb + (size_t)row * (DD * 2) + k0 * 2 + sxb, BshB + ldso);
    }
    __syncthreads();
#pragma unroll
    for (int ks = 0; ks < 2; ++ks) {
      bf16x8 af[4], bfr[4];
      int colb = ks * 64 + ((lane >> 4) << 4);
#pragma unroll
      for (int mi = 0; mi < 4; ++mi) {
        int row = wr * 64 + mi * 16 + (lane & 15);
        af[mi] = *(const bf16x8*)(AshB + row * 128 + (colb ^ ((row & 7) << 4)));
      }
#pragma unroll
      for (int ni = 0; ni < 4; ++ni) {
        int row = wc * 64 + ni * 16 + (lane & 15);
        bfr[ni] = *(const bf16x8*)(BshB + row * 128 + (colb ^ ((row & 7) << 4)));
      }
#pragma unroll
      for (int mi = 0; mi < 4; ++mi)
#pragma unroll
        for (int ni = 0; ni < 4; ++ni)
          acc[mi][ni] = __builtin_amdgcn_mfma_f32_16x16x32_bf16(af[mi], bfr[ni], acc[mi][ni], 0, 0, 0);
    }
  }
#pragma unroll
  for (int mi = 0; mi < 4; ++mi)
#pragma unroll
    for (int r = 0; r < 4; ++r) {
      int t = brow + wr * 64 + mi * 16 + ((lane >> 4) << 2) + r;
#pragma unroll
      for (int ni = 0; ni < 4; ++ni) {
        int o = bcol + wc * 64 + ni * 16 + (lane & 15);
        out[(size_t)t * DD + o] = acc[mi][ni][r] + bias[o];
      }
    }
}

// ---------------- launch ----------------
extern "C" void kernel_launch(void* const* d_in, const int* in_sizes, int n_in,
                              void* d_out, int out_size, void* d_ws, size_t ws_size,
                              hipStream_t stream) {
  const float* q  = (const float*)d_in[0];
  const float* k  = (const float*)d_in[1];
  const float* v  = (const float*)d_in[2];
  const int* pos  = (const int*)d_in[3];
  const float* wq = (const float*)d_in[4];
  const float* wk = (const float*)d_in[5];
  const float* wv = (const float*)d_in[6];
  const float* wo = (const float*)d_in[7];
  const float* wob = (const float*)d_in[8];
  float* out = (float*)d_out;
  char* ws = (char*)d_ws;

  const size_t MB = 1u << 20;
  unsigned short* XQ = (unsigned short*)(ws + 0 * MB);
  unsigned short* XK = (unsigned short*)(ws + 4 * MB);
  unsigned short* XV = (unsigned short*)(ws + 8 * MB);
  unsigned short* WQ = (unsigned short*)(ws + 12 * MB);
  unsigned short* WK = (unsigned short*)(ws + 14 * MB);
  unsigned short* WV = (unsigned short*)(ws + 16 * MB);
  unsigned short* WO = (unsigned short*)(ws + 18 * MB);
  unsigned short* QH = (unsigned short*)(ws + 20 * MB);
  unsigned short* KH = (unsigned short*)(ws + 24 * MB);
  unsigned short* VT = (unsigned short*)(ws + 28 * MB);
  unsigned short* AOb = (unsigned short*)(ws + 32 * MB);
  float* COS = (float*)(ws + 36 * MB);
  float* SIN = (float*)(ws + 36 * MB + 262144);

  hipLaunchKernelGGL(cvt_all, dim3(5120), dim3(256), 0, stream,
                     q, k, v, wq, wk, wv, wo, XQ, XK, XV, WQ, WK, WV, WO);
  hipLaunchKernelGGL(rope_tab, dim3(256), dim3(256), 0, stream, pos, COS, SIN);
  hipLaunchKernelGGL(gemm_qkv, dim3(16, 8, 3), dim3(256), 0, stream,
                     XQ, XK, XV, WQ, WK, WV, QH, KH, VT, COS, SIN);
  hipLaunchKernelGGL(attn, dim3(16, 16), dim3(256), 0, stream, QH, KH, VT, AOb);
  hipLaunchKernelGGL(gemm_o, dim3(16, 8), dim3(256), 0, stream, AOb, WO, wob, out);
}

// Round 2
// 130.633 us; speedup vs baseline: 1.0851x; 1.0851x over previous
//
#include <hip/hip_runtime.h>
#include <hip/hip_bf16.h>
#include <stdint.h>

#define TT 2048
#define DD 1024
#define NH 16
#define DK 64

typedef __attribute__((ext_vector_type(8))) short bf16x8;
typedef __attribute__((ext_vector_type(4))) float f32x4;
typedef __attribute__((ext_vector_type(8))) unsigned short u16x8;
typedef __attribute__((ext_vector_type(4))) unsigned short u16x4;

__device__ __forceinline__ unsigned short f2bf(float f) {
  union { float f; unsigned u; } x; x.f = f;
  unsigned r = (x.u + 0x7FFFu + ((x.u >> 16) & 1u)) >> 16;
  return (unsigned short)r;
}

__device__ __forceinline__ void gload16(const void* g, void* l) {
  __builtin_amdgcn_global_load_lds(
      (const __attribute__((address_space(1))) unsigned int*)g,
      (__attribute__((address_space(3))) unsigned int*)l, 16, 0, 0);
}

// ---------------- convert f32 -> bf16 ----------------
__global__ __launch_bounds__(256) void cvt_all(
    const float* __restrict__ q, const float* __restrict__ k, const float* __restrict__ v,
    const float* __restrict__ wq, const float* __restrict__ wk, const float* __restrict__ wv,
    const float* __restrict__ wo,
    unsigned short* __restrict__ oq, unsigned short* __restrict__ ok, unsigned short* __restrict__ ov,
    unsigned short* __restrict__ owq, unsigned short* __restrict__ owk, unsigned short* __restrict__ owv,
    unsigned short* __restrict__ owo) {
  int b = blockIdx.x;
  const float* src; unsigned short* dst; int sb;
  if (b < 1024)      { src = q;  dst = oq;  sb = b; }
  else if (b < 2048) { src = k;  dst = ok;  sb = b - 1024; }
  else if (b < 3072) { src = v;  dst = ov;  sb = b - 2048; }
  else if (b < 3584) { src = wq; dst = owq; sb = b - 3072; }
  else if (b < 4096) { src = wk; dst = owk; sb = b - 3584; }
  else if (b < 4608) { src = wv; dst = owv; sb = b - 4096; }
  else               { src = wo; dst = owo; sb = b - 4608; }
  size_t i0 = (size_t)sb * 2048 + (size_t)threadIdx.x * 8;
  f32x4 a = *(const f32x4*)(src + i0);
  f32x4 c = *(const f32x4*)(src + i0 + 4);
  u16x8 r;
#pragma unroll
  for (int j = 0; j < 4; ++j) { r[j] = f2bf(a[j]); r[j + 4] = f2bf(c[j]); }
  *(u16x8*)(dst + i0) = r;
}

// ---------------- RoPE cos/sin table ----------------
__global__ __launch_bounds__(256) void rope_tab(const int* __restrict__ pos,
                                                float* __restrict__ cosT,
                                                float* __restrict__ sinT) {
  int idx = blockIdx.x * 256 + threadIdx.x;  // 2048*32
  int t = idx >> 5, i = idx & 31;
  float inv = exp2f((float)i * -0.41524101186092028f);  // 10000^(-i/32)
  float ang = (float)pos[t] * inv;
  cosT[idx] = cosf(ang);
  sinT[idx] = sinf(ang);
}

// ---------------- fused QKV projection + RoPE ----------------
__global__ __launch_bounds__(256) void gemm_qkv(
    const unsigned short* __restrict__ xq, const unsigned short* __restrict__ xk,
    const unsigned short* __restrict__ xv,
    const unsigned short* __restrict__ wqb, const unsigned short* __restrict__ wkb,
    const unsigned short* __restrict__ wvb,
    unsigned short* __restrict__ Qh, unsigned short* __restrict__ Kh,
    unsigned short* __restrict__ Vt,
    const float* __restrict__ cosT, const float* __restrict__ sinT) {
  __shared__ unsigned short Ash[128 * 64];
  __shared__ unsigned short Bsh[128 * 64];
  const int z = blockIdx.z;
  const unsigned short* A = (z == 0) ? xq : (z == 1) ? xk : xv;
  const unsigned short* W = (z == 0) ? wqb : (z == 1) ? wkb : wvb;
  const int brow = blockIdx.x * 128;
  const int bcol = blockIdx.y * 128;
  const int tid = threadIdx.x;
  const int lane = tid & 63;
  const int w = tid >> 6;
  const int wr = w >> 1, wc = w & 1;
  const char* Ab = (const char*)A + (size_t)brow * (DD * 2);
  const char* Wb = (const char*)W + (size_t)bcol * (DD * 2);
  char* AshB = (char*)Ash;
  char* BshB = (char*)Bsh;
  f32x4 acc[4][4];
#pragma unroll
  for (int mi = 0; mi < 4; ++mi)
#pragma unroll
    for (int ni = 0; ni < 4; ++ni)
#pragma unroll
      for (int r = 0; r < 4; ++r) acc[mi][ni][r] = 0.0f;

  for (int k0 = 0; k0 < DD; k0 += 64) {
    __syncthreads();
#pragma unroll
    for (int it = 0; it < 4; ++it) {
      int c = it * 256 + tid;
      int row = c >> 3;
      int xb = (c & 7) << 4;
      int sxb = xb ^ ((row & 7) << 4);
      int ldso = (it * 256 + (tid & 192)) << 4;
      gload16(Ab + (size_t)row * (DD * 2) + k0 * 2 + sxb, AshB + ldso);
      gload16(Wb + (size_t)row * (DD * 2) + k0 * 2 + sxb, BshB + ldso);
    }
    __syncthreads();
#pragma unroll
    for (int ks = 0; ks < 2; ++ks) {
      bf16x8 af[4], bfr[4];
      int colb = ks * 64 + ((lane >> 4) << 4);
#pragma unroll
      for (int mi = 0; mi < 4; ++mi) {
        int row = wr * 64 + mi * 16 + (lane & 15);
        af[mi] = *(const bf16x8*)(AshB + row * 128 + (colb ^ ((row & 7) << 4)));
      }
#pragma unroll
      for (int ni = 0; ni < 4; ++ni) {
        int row = wc * 64 + ni * 16 + (lane & 15);
        bfr[ni] = *(const bf16x8*)(BshB + row * 128 + (colb ^ ((row & 7) << 4)));
      }
#pragma unroll
      for (int mi = 0; mi < 4; ++mi)
#pragma unroll
        for (int ni = 0; ni < 4; ++ni)
          acc[mi][ni] = __builtin_amdgcn_mfma_f32_16x16x32_bf16(af[mi], bfr[ni], acc[mi][ni], 0, 0, 0);
    }
  }

  const int hcol = bcol + wc * 64;
  const int h = hcol >> 6;
  if (z < 2) {
    unsigned short* OUT = (z == 0) ? Qh : Kh;
    const float sc = (z == 0) ? 0.125f : 1.0f;
#pragma unroll
    for (int mi = 0; mi < 4; ++mi) {
#pragma unroll
      for (int r = 0; r < 4; ++r) {
        int t = brow + wr * 64 + mi * 16 + ((lane >> 4) << 2) + r;
#pragma unroll
        for (int ni = 0; ni < 2; ++ni) {
          int dl = ni * 16 + (lane & 15);
          float cv = cosT[t * 32 + dl];
          float sv = sinT[t * 32 + dl];
          float x1 = acc[mi][ni][r];
          float x2 = acc[mi][ni + 2][r];
          size_t base = ((size_t)h * TT + t) * DK + dl;
          OUT[base] = f2bf((x1 * cv - x2 * sv) * sc);
          OUT[base + 32] = f2bf((x2 * cv + x1 * sv) * sc);
        }
      }
    }
  } else {
#pragma unroll
    for (int mi = 0; mi < 4; ++mi) {
#pragma unroll
      for (int ni = 0; ni < 4; ++ni) {
        int dh = ni * 16 + (lane & 15);
        int t0 = brow + wr * 64 + mi * 16 + ((lane >> 4) << 2);
        u16x4 pk;
#pragma unroll
        for (int r = 0; r < 4; ++r) pk[r] = f2bf(acc[mi][ni][r]);
        *(u16x4*)((char*)Vt + (((size_t)h * DK + dh) * TT + t0) * 2) = pk;
      }
    }
  }
}

// ---------------- causal flash attention (wave-independent, no barriers) ----
// grid (32 pair-blocks, 16 heads), 128 threads = 2 waves.
// wave 0 -> q-wave j, wave 1 -> q-wave 63-j  (uniform work per block)
__device__ __forceinline__ void load_kfrag(const char* Kb, int k0, int lane,
                                           bf16x8 kf[2][4]) {
#pragma unroll
  for (int ks = 0; ks < 2; ++ks)
#pragma unroll
    for (int ni = 0; ni < 4; ++ni) {
      const char* p = Kb + (size_t)(k0 + ni * 16 + (lane & 15)) * 128 + ks * 64 +
                      ((lane >> 4) << 4);
      kf[ks][ni] = *(const bf16x8*)p;
    }
}

__device__ __forceinline__ void load_vfrag(const char* Vb, int k0, int lane,
                                           bf16x8 vf[2][4]) {
#pragma unroll
  for (int ks = 0; ks < 2; ++ks)
#pragma unroll
    for (int ni = 0; ni < 4; ++ni) {
      const char* p = Vb + (size_t)(ni * 16 + (lane & 15)) * (TT * 2) +
                      (k0 + ks * 32) * 2 + ((lane >> 4) << 4);
      vf[ks][ni] = *(const bf16x8*)p;
    }
}

__global__ __launch_bounds__(128) void attn(
    const unsigned short* __restrict__ Qh, const unsigned short* __restrict__ Kh,
    const unsigned short* __restrict__ Vt, unsigned short* __restrict__ AO) {
  __shared__ unsigned short Psh[2][32 * 64];
  const int h = blockIdx.y;
  const int tid = threadIdx.x;
  const int lane = tid & 63;
  const int w = tid >> 6;
  const int qw = (w == 0) ? (int)blockIdx.x : 63 - (int)blockIdx.x;
  const int q0w = qw * 32;
  const int NT = qw / 2 + 1;  // causal tiles of 64 keys
  char* PshB = (char*)&Psh[w][0];
  const char* Kb = (const char*)Kh + (size_t)h * TT * DK * 2;
  const char* Vb = (const char*)Vt + (size_t)h * DK * TT * 2;

  bf16x8 qf[2][2];
#pragma unroll
  for (int mi = 0; mi < 2; ++mi)
#pragma unroll
    for (int ks = 0; ks < 2; ++ks) {
      const unsigned short* p =
          Qh + ((size_t)h * TT + q0w + mi * 16 + (lane & 15)) * DK + ks * 32 + ((lane >> 4) << 3);
      qf[mi][ks] = *(const bf16x8*)p;
    }

  f32x4 accO[2][4];
  float mrow[2][4], lrow[2][4];
#pragma unroll
  for (int mi = 0; mi < 2; ++mi) {
#pragma unroll
    for (int ni = 0; ni < 4; ++ni)
#pragma unroll
      for (int r = 0; r < 4; ++r) accO[mi][ni][r] = 0.0f;
#pragma unroll
    for (int r = 0; r < 4; ++r) { mrow[mi][r] = -1e30f; lrow[mi][r] = 0.0f; }
  }

  bf16x8 kfA[2][4], kfB[2][4], vf[2][4];
  load_kfrag(Kb, 0, lane, kfA);
#pragma unroll
  for (int ks = 0; ks < 2; ++ks)
#pragma unroll
    for (int ni = 0; ni < 4; ++ni) kfB[ks][ni] = kfA[ks][ni];

  for (int kt = 0; kt < NT; ++kt) {
    const int k0 = kt * 64;
    load_vfrag(Vb, k0, lane, vf);  // issue early; QK+softmax covers latency
    f32x4 s[2][4];
#pragma unroll
    for (int mi = 0; mi < 2; ++mi)
#pragma unroll
      for (int ni = 0; ni < 4; ++ni)
#pragma unroll
        for (int r = 0; r < 4; ++r) s[mi][ni][r] = 0.0f;
#pragma unroll
    for (int ks = 0; ks < 2; ++ks)
#pragma unroll
      for (int mi = 0; mi < 2; ++mi)
#pragma unroll
        for (int ni = 0; ni < 4; ++ni)
          s[mi][ni] = __builtin_amdgcn_mfma_f32_16x16x32_bf16(qf[mi][ks], kfA[ks][ni], s[mi][ni], 0, 0, 0);
    if (kt + 1 < NT) load_kfrag(Kb, k0 + 64, lane, kfB);  // prefetch next K tile

    if (kt == NT - 1) {  // only the diagonal tile needs the causal mask
#pragma unroll
      for (int mi = 0; mi < 2; ++mi)
#pragma unroll
        for (int ni = 0; ni < 4; ++ni)
#pragma unroll
          for (int r = 0; r < 4; ++r) {
            int qq = q0w + mi * 16 + ((lane >> 4) << 2) + r;
            int kk = k0 + ni * 16 + (lane & 15);
            if (kk > qq) s[mi][ni][r] = -1e30f;
          }
    }
#pragma unroll
    for (int mi = 0; mi < 2; ++mi) {
      f32x4 rmx = s[mi][0];
#pragma unroll
      for (int ni = 1; ni < 4; ++ni)
#pragma unroll
        for (int r = 0; r < 4; ++r) rmx[r] = fmaxf(rmx[r], s[mi][ni][r]);
#pragma unroll
      for (int d = 1; d < 16; d <<= 1)
#pragma unroll
        for (int r = 0; r < 4; ++r) rmx[r] = fmaxf(rmx[r], __shfl_xor(rmx[r], d, 64));
      float alpha[4];
#pragma unroll
      for (int r = 0; r < 4; ++r) {
        float mo = mrow[mi][r];
        float mn = fmaxf(mo, rmx[r]);
        alpha[r] = __expf(mo - mn);
        mrow[mi][r] = mn;
        lrow[mi][r] *= alpha[r];
      }
#pragma unroll
      for (int ni = 0; ni < 4; ++ni)
#pragma unroll
        for (int r = 0; r < 4; ++r) accO[mi][ni][r] *= alpha[r];
      f32x4 rsum;
#pragma unroll
      for (int r = 0; r < 4; ++r) rsum[r] = 0.0f;
#pragma unroll
      for (int ni = 0; ni < 4; ++ni)
#pragma unroll
        for (int r = 0; r < 4; ++r) {
          float p = __expf(s[mi][ni][r] - mrow[mi][r]);
          s[mi][ni][r] = p;
          rsum[r] += p;
        }
#pragma unroll
      for (int d = 1; d < 16; d <<= 1)
#pragma unroll
        for (int r = 0; r < 4; ++r) rsum[r] += __shfl_xor(rsum[r], d, 64);
#pragma unroll
      for (int r = 0; r < 4; ++r) lrow[mi][r] += rsum[r];
      // write P (bf16) to per-wave LDS, swizzled (wave-local, no barrier)
#pragma unroll
      for (int ni = 0; ni < 4; ++ni)
#pragma unroll
        for (int r = 0; r < 4; ++r) {
          int row = mi * 16 + ((lane >> 4) << 2) + r;
          int cb = (ni * 16 + (lane & 15)) * 2;
          *(short*)(PshB + row * 128 + (cb ^ ((row & 7) << 4))) = (short)f2bf(s[mi][ni][r]);
        }
    }
    asm volatile("" ::: "memory");  // order P writes before P reads (wave-local)
#pragma unroll
    for (int ks = 0; ks < 2; ++ks) {
      int colb = ks * 64 + ((lane >> 4) << 4);
      bf16x8 pf[2];
#pragma unroll
      for (int mi = 0; mi < 2; ++mi) {
        int row = mi * 16 + (lane & 15);
        pf[mi] = *(const bf16x8*)(PshB + row * 128 + (colb ^ ((row & 7) << 4)));
      }
#pragma unroll
      for (int mi = 0; mi < 2; ++mi)
#pragma unroll
        for (int ni = 0; ni < 4; ++ni)
          accO[mi][ni] = __builtin_amdgcn_mfma_f32_16x16x32_bf16(pf[mi], vf[ks][ni], accO[mi][ni], 0, 0, 0);
    }
#pragma unroll
    for (int ks = 0; ks < 2; ++ks)
#pragma unroll
      for (int ni = 0; ni < 4; ++ni) kfA[ks][ni] = kfB[ks][ni];
  }
  // epilogue: normalize, store bf16 [t][h*64+d]
#pragma unroll
  for (int mi = 0; mi < 2; ++mi)
#pragma unroll
    for (int ni = 0; ni < 4; ++ni)
#pragma unroll
      for (int r = 0; r < 4; ++r) {
        int t = q0w + mi * 16 + ((lane >> 4) << 2) + r;
        int dh = ni * 16 + (lane & 15);
        float v = accO[mi][ni][r] / lrow[mi][r];
        AO[(size_t)t * DD + h * DK + dh] = f2bf(v);
      }
}

// ---------------- output projection + bias (f32 out) ----------------
__global__ __launch_bounds__(256) void gemm_o(
    const unsigned short* __restrict__ A, const unsigned short* __restrict__ W,
    const float* __restrict__ bias, float* __restrict__ out) {
  __shared__ unsigned short Ash[128 * 64];
  __shared__ unsigned short Bsh[128 * 64];
  const int brow = blockIdx.x * 128;
  const int bcol = blockIdx.y * 128;
  const int tid = threadIdx.x;
  const int lane = tid & 63;
  const int w = tid >> 6;
  const int wr = w >> 1, wc = w & 1;
  const char* Ab = (const char*)A + (size_t)brow * (DD * 2);
  const char* Wb = (const char*)W + (size_t)bcol * (DD * 2);
  char* AshB = (char*)Ash;
  char* BshB = (char*)Bsh;
  f32x4 acc[4][4];
#pragma unroll
  for (int mi = 0; mi < 4; ++mi)
#pragma unroll
    for (int ni = 0; ni < 4; ++ni)
#pragma unroll
      for (int r = 0; r < 4; ++r) acc[mi][ni][r] = 0.0f;

  for (int k0 = 0; k0 < DD; k0 += 64) {
    __syncthreads();
#pragma unroll
    for (int it = 0; it < 4; ++it) {
      int c = it * 256 + tid;
      int row = c >> 3;
      int xb = (c & 7) << 4;
      int sxb = xb ^ ((row & 7) << 4);
      int ldso = (it * 256 + (tid & 192)) << 4;
      gload16(Ab + (size_t)row * (DD * 2) + k0 * 2 + sxb, AshB + ldso);
      gload16(Wb + (size_t)row * (DD * 2) + k0 * 2 + sxb, BshB + ldso);
    }
    __syncthreads();
#pragma unroll
    for (int ks = 0; ks < 2; ++ks) {
      bf16x8 af[4], bfr[4];
      int colb = ks * 64 + ((lane >> 4) << 4);
#pragma unroll
      for (int mi = 0; mi < 4; ++mi) {
        int row = wr * 64 + mi * 16 + (lane & 15);
        af[mi] = *(const bf16x8*)(AshB + row * 128 + (colb ^ ((row & 7) << 4)));
      }
#pragma unroll
      for (int ni = 0; ni < 4; ++ni) {
        int row = wc * 64 + ni * 16 + (lane & 15);
        bfr[ni] = *(const bf16x8*)(BshB + row * 128 + (colb ^ ((row & 7) << 4)));
      }
#pragma unroll
      for (int mi = 0; mi < 4; ++mi)
#pragma unroll
        for (int ni = 0; ni < 4; ++ni)
          acc[mi][ni] = __builtin_amdgcn_mfma_f32_16x16x32_bf16(af[mi], bfr[ni], acc[mi][ni], 0, 0, 0);
    }
  }
#pragma unroll
  for (int mi = 0; mi < 4; ++mi)
#pragma unroll
    for (int r = 0; r < 4; ++r) {
      int t = brow + wr * 64 + mi * 16 + ((lane >> 4) << 2) + r;
#pragma unroll
      for (int ni = 0; ni < 4; ++ni) {
        int o = bcol + wc * 64 + ni * 16 + (lane & 15);
        out[(size_t)t * DD + o] = acc[mi][ni][r] + bias[o];
      }
    }
}

// ---------------- launch ----------------
extern "C" void kernel_launch(void* const* d_in, const int* in_sizes, int n_in,
                              void* d_out, int out_size, void* d_ws, size_t ws_size,
                              hipStream_t stream) {
  const float* q  = (const float*)d_in[0];
  const float* k  = (const float*)d_in[1];
  const float* v  = (const float*)d_in[2];
  const int* pos  = (const int*)d_in[3];
  const float* wq = (const float*)d_in[4];
  const float* wk = (const float*)d_in[5];
  const float* wv = (const float*)d_in[6];
  const float* wo = (const float*)d_in[7];
  const float* wob = (const float*)d_in[8];
  float* out = (float*)d_out;
  char* ws = (char*)d_ws;

  const size_t MB = 1u << 20;
  unsigned short* XQ = (unsigned short*)(ws + 0 * MB);
  unsigned short* XK = (unsigned short*)(ws + 4 * MB);
  unsigned short* XV = (unsigned short*)(ws + 8 * MB);
  unsigned short* WQ = (unsigned short*)(ws + 12 * MB);
  unsigned short* WK = (unsigned short*)(ws + 14 * MB);
  unsigned short* WV = (unsigned short*)(ws + 16 * MB);
  unsigned short* WO = (unsigned short*)(ws + 18 * MB);
  unsigned short* QH = (unsigned short*)(ws + 20 * MB);
  unsigned short* KH = (unsigned short*)(ws + 24 * MB);
  unsigned short* VT = (unsigned short*)(ws + 28 * MB);
  unsigned short* AOb = (unsigned short*)(ws + 32 * MB);
  float* COS = (float*)(ws + 36 * MB);
  float* SIN = (float*)(ws + 36 * MB + 262144);

  hipLaunchKernelGGL(cvt_all, dim3(5120), dim3(256), 0, stream,
                     q, k, v, wq, wk, wv, wo, XQ, XK, XV, WQ, WK, WV, WO);
  hipLaunchKernelGGL(rope_tab, dim3(256), dim3(256), 0, stream, pos, COS, SIN);
  hipLaunchKernelGGL(gemm_qkv, dim3(16, 8, 3), dim3(256), 0, stream,
                     XQ, XK, XV, WQ, WK, WV, QH, KH, VT, COS, SIN);
  hipLaunchKernelGGL(attn, dim3(32, 16), dim3(128), 0, stream, QH, KH, VT, AOb);
  hipLaunchKernelGGL(gemm_o, dim3(16, 8), dim3(256), 0, stream, AOb, WO, wob, out);
}